// Round 7
// baseline (1498.693 us; speedup 1.0000x reference)
//
#include <hip/hip_runtime.h>

typedef unsigned int u32;
typedef unsigned long long u64;
typedef float f32x4 __attribute__((ext_vector_type(4)));
typedef short short8 __attribute__((ext_vector_type(8)));

// B=64, S=128, D=512, T=64. 4 groups x 16 batches.
// ws byte offsets:
#define OFF_UKB 0u          // u32[64*128*256] bf16 Uk
#define OFF_ECB 8388608u    // u32[64*128*256] bf16 e_all
#define OFF_EX  16777216u   // per-group exchange
#define G_BYTES 200704u
// group layout (bytes): HX u64[2][2048] @0 | CX u64[2][2048] @32768 |
//                       QX u64[2][8192] @65536 | FH 32x64B @196608 | FC 16x64B @198656

#define OFF_OUT_HT  12288u
#define OFF_OUT_ATT 45056u

#define NBLK 192
#define NTHR 512

__device__ __forceinline__ float fast_rcp(float x) { return __builtin_amdgcn_rcpf(x); }
__device__ __forceinline__ float tanh5(float x) {
    float e = __expf(2.f * x);
    return 1.f - 2.f * fast_rcp(e + 1.f);
}
__device__ __forceinline__ float sigm_f(float x) { return fast_rcp(1.f + __expf(-x)); }

__device__ __forceinline__ u32 packbf2(float a, float b) {
    u32 ua = __float_as_uint(a); ua += 0x7FFFu + ((ua >> 16) & 1u);
    u32 ub = __float_as_uint(b); ub += 0x7FFFu + ((ub >> 16) & 1u);
    return (ua >> 16) | (ub & 0xFFFF0000u);
}
__device__ __forceinline__ float2 unpackbf2(u32 u) {
    return make_float2(__uint_as_float(u << 16), __uint_as_float(u & 0xFFFF0000u));
}

// relaxed agent-scope accessors: per-access cache bypass, no cache-wide inv/wb
__device__ __forceinline__ u64 cload64(const u64* p) {
    return __hip_atomic_load(p, __ATOMIC_RELAXED, __HIP_MEMORY_SCOPE_AGENT);
}
__device__ __forceinline__ void cstore64(u64* p, u64 v) {
    __hip_atomic_store(p, v, __ATOMIC_RELAXED, __HIP_MEMORY_SCOPE_AGENT);
}
__device__ __forceinline__ u32 cload32(const u32* p) {
    return __hip_atomic_load(p, __ATOMIC_RELAXED, __HIP_MEMORY_SCOPE_AGENT);
}
__device__ __forceinline__ void cstore32(u32* p, u32 v) {
    __hip_atomic_store(p, v, __ATOMIC_RELAXED, __HIP_MEMORY_SCOPE_AGENT);
}

union U16 { u64 d[2]; short8 s; };
union UQ  { u32 u[4]; short8 s; };

// ---------------- prep: Uk GEMM(bf16) + e_all pack + H0 + flags ----------------
__global__ __launch_bounds__(256) void prep_kernel(
    const float* __restrict__ e_all, const float* __restrict__ e_last,
    const float* __restrict__ Ua_w,  const float* __restrict__ Ua_b,
    float* __restrict__ ws)
{
    u32* UKB = (u32*)((char*)ws + OFF_UKB);
    u32* ECB = (u32*)((char*)ws + OFF_ECB);

    __shared__ float a_s[16 * 512];
    const int blk = blockIdx.x, tid = threadIdx.x;
    const int gtid = blk * 256 + tid, gstride = 512 * 256;

    // flags zero: 4 groups x 768 u32 (FH 512 + FC 256)
    for (int i = gtid; i < 3072; i += gstride) {
        const int g = i / 768, j = i - g * 768;
        cstore32((u32*)((char*)ws + OFF_EX + (size_t)g * G_BYTES + 196608) + j, 0u);
    }

    const int r0 = blk * 16;
    for (int i = tid; i < 16 * 512; i += 256) a_s[i] = e_all[(size_t)r0 * 512 + i];
    __syncthreads();

    const int jj = tid & 63, sub = tid >> 6;
    const int rbase = sub * 4 * 512;
    for (int jo = 0; jo < 4; ++jo) {
        const int j0 = (jo * 64 + jj) * 2;
        float a0[4], a1[4];
        #pragma unroll
        for (int rr = 0; rr < 4; ++rr) { a0[rr] = 0.f; a1[rr] = 0.f; }
        const float* wp = Ua_w + j0;
        #pragma unroll 4
        for (int k = 0; k < 512; ++k) {
            const float w0 = wp[(size_t)k * 512];
            const float w1 = wp[(size_t)k * 512 + 1];
            #pragma unroll
            for (int rr = 0; rr < 4; ++rr) {
                const float hv = a_s[rbase + rr * 512 + k];
                a0[rr] = fmaf(w0, hv, a0[rr]);
                a1[rr] = fmaf(w1, hv, a1[rr]);
            }
        }
        const float bb0 = Ua_b[j0], bb1 = Ua_b[j0 + 1];
        #pragma unroll
        for (int rr = 0; rr < 4; ++rr) {
            const int row = r0 + sub * 4 + rr;
            UKB[(size_t)row * 256 + (j0 >> 1)] = packbf2(a0[rr] + bb0, a1[rr] + bb1);
        }
    }

    for (int i = gtid; i < 2097152; i += gstride)
        ECB[i] = packbf2(e_all[2 * i], e_all[2 * i + 1]);

    // H0 -> HX slot 0 (u64 = 4 bf16), bypass stores
    for (int i = gtid; i < 8192; i += gstride) {
        const int g = i >> 11, i2 = i & 2047;
        const float* ep = e_last + ((size_t)(g * 16 + (i2 >> 7)) * 512) + 4 * (i2 & 127);
        u64* HX = (u64*)((char*)ws + OFF_EX + (size_t)g * G_BYTES);
        cstore64(HX + i2, (u64)packbf2(ep[0], ep[1]) | ((u64)packbf2(ep[2], ep[3]) << 32));
    }
}

// ---------------- persistent decode: per group 16 attn + 32 GRU blocks ----------------
__global__ __launch_bounds__(512, 1) void decode_kernel(
    const float* __restrict__ e_last,
    const float* __restrict__ Wa_w,  const float* __restrict__ Wa_b,
    const float* __restrict__ Va_w,
    const float* __restrict__ W_ih,  const float* __restrict__ W_hh,
    const float* __restrict__ b_ih,  const float* __restrict__ b_hh,
    const float* __restrict__ Wo_w,  const float* __restrict__ Wo_b,
    float* __restrict__ out, float* __restrict__ ws)
{
    __shared__ char smraw[16640];

    const u32* UKB = (const u32*)((char*)ws + OFF_UKB);
    const u32* ECB = (const u32*)((char*)ws + OFF_ECB);

    const int tid = threadIdx.x;
    const int bi  = blockIdx.x;
    const int g   = bi / 48, r = bi % 48;
    const int lane = tid & 63, wv = tid >> 6;

    char* gbase = (char*)ws + OFF_EX + (size_t)g * G_BYTES;
    u64* HX = (u64*)gbase;
    u64* CX = (u64*)(gbase + 32768);
    u64* QX = (u64*)(gbase + 65536);
    u32* FH = (u32*)(gbase + 196608);
    u32* FC = (u32*)(gbase + 198656);

    if (r < 16) {
        // ===================== attention block: one per b =====================
        const int bl = r, b = g * 16 + bl;
        float* q_s  = (float*)smraw;               // 512
        float* va_s = (float*)(smraw + 2048);      // 512
        float* sc_s = (float*)(smraw + 4096);      // 128
        float* w_s  = (float*)(smraw + 4608);      // 128
        float* red  = (float*)(smraw + 5120);      // 16
        float* psq  = (float*)(smraw + 8192);      // 2048 floats

        va_s[tid] = Va_w[tid];

        for (int t = 0; t < 64; ++t) {
            const int slot = t & 1;
            const u64* QxS = QX + slot * 8192;
            u64* CxS = CX + slot * 2048;
            const u32 tagv = (u32)(t + 1);

            // ---- q: tag-in-data poll (one MALL round trip) ----
            {
                const u64* qp = QxS + (size_t)bl * 512 + tid;
                u64 v = cload64(qp);
                while ((u32)(v >> 32) != tagv) { __builtin_amdgcn_s_sleep(1); v = cload64(qp); }
                q_s[tid] = __uint_as_float((u32)v);
            }
            __syncthreads();

            // ---- scores: tanh(q + Uk) . Va (Uk bf16 from L2) ----
            {
                const int kl = lane & 15;
                float4 qa[4], qb[4], vaa[4], vab[4];
                const float4* q4 = (const float4*)q_s;
                const float4* v4 = (const float4*)va_s;
                #pragma unroll
                for (int it = 0; it < 4; ++it) {
                    qa[it] = q4[(it * 16 + kl) * 2];  qb[it] = q4[(it * 16 + kl) * 2 + 1];
                    vaa[it] = v4[(it * 16 + kl) * 2]; vab[it] = v4[(it * 16 + kl) * 2 + 1];
                }
                const int sbase = wv * 16 + (lane >> 4);
                #pragma unroll
                for (int sg = 0; sg < 4; ++sg) {
                    const int s = sbase + sg * 4;
                    const uint4* uk4 = (const uint4*)(UKB + ((size_t)b * 128 + s) * 256);
                    float acc = 0.f;
                    #pragma unroll
                    for (int it = 0; it < 4; ++it) {
                        const uint4 u = uk4[it * 16 + kl];
                        const float2 u0 = unpackbf2(u.x), u1 = unpackbf2(u.y);
                        const float2 u2 = unpackbf2(u.z), u3 = unpackbf2(u.w);
                        acc = fmaf(tanh5(qa[it].x + u0.x), vaa[it].x, acc);
                        acc = fmaf(tanh5(qa[it].y + u0.y), vaa[it].y, acc);
                        acc = fmaf(tanh5(qa[it].z + u1.x), vaa[it].z, acc);
                        acc = fmaf(tanh5(qa[it].w + u1.y), vaa[it].w, acc);
                        acc = fmaf(tanh5(qb[it].x + u2.x), vab[it].x, acc);
                        acc = fmaf(tanh5(qb[it].y + u2.y), vab[it].y, acc);
                        acc = fmaf(tanh5(qb[it].z + u3.x), vab[it].z, acc);
                        acc = fmaf(tanh5(qb[it].w + u3.y), vab[it].w, acc);
                    }
                    acc += __shfl_xor(acc, 1); acc += __shfl_xor(acc, 2);
                    acc += __shfl_xor(acc, 4); acc += __shfl_xor(acc, 8);
                    if (kl == 0) sc_s[s] = acc;   // Va_b: softmax-invariant
                }
            }
            __syncthreads();

            // ---- softmax ----
            if (tid < 64) {
                float mx = fmaxf(sc_s[tid], sc_s[tid + 64]);
                #pragma unroll
                for (int off = 32; off > 0; off >>= 1) mx = fmaxf(mx, __shfl_down(mx, off));
                if (tid == 0) red[0] = mx;
            }
            __syncthreads();
            if (tid < 128) w_s[tid] = __expf(sc_s[tid] - red[0]);
            __syncthreads();
            if (tid < 64) {
                float sm = w_s[tid] + w_s[tid + 64];
                #pragma unroll
                for (int off = 32; off > 0; off >>= 1) sm += __shfl_down(sm, off);
                if (tid == 0) red[1] = fast_rcp(sm);
            }
            __syncthreads();
            if (tid < 128) {
                const float wn = w_s[tid] * red[1];
                w_s[tid] = wn;
                out[OFF_OUT_ATT + ((size_t)b * 64 + t) * 128 + tid] = wn;
            }
            __syncthreads();

            // ---- ctx = w @ e_all[b] (bf16, s-split-4) ----
            {
                const int dq = tid & 127, sg = tid >> 7;
                const uint2* ep = (const uint2*)(ECB + (size_t)b * 32768);
                float4 a = {0.f, 0.f, 0.f, 0.f};
                #pragma unroll 4
                for (int si = 0; si < 32; ++si) {
                    const int s = sg * 32 + si;
                    const float wgt = w_s[s];
                    const uint2 e2 = ep[(size_t)s * 128 + dq];
                    const float2 e0 = unpackbf2(e2.x), e1 = unpackbf2(e2.y);
                    a.x = fmaf(wgt, e0.x, a.x);
                    a.y = fmaf(wgt, e0.y, a.y);
                    a.z = fmaf(wgt, e1.x, a.z);
                    a.w = fmaf(wgt, e1.y, a.w);
                }
                ((float4*)psq)[sg * 128 + dq] = a;
            }
            __syncthreads();
            if (tid < 128) {
                const float4* p4 = (const float4*)psq;
                float4 a = p4[tid], b2 = p4[128 + tid], c2 = p4[256 + tid], d2 = p4[384 + tid];
                const float rx = a.x + b2.x + c2.x + d2.x;
                const float ry = a.y + b2.y + c2.y + d2.y;
                const float rz = a.z + b2.z + c2.z + d2.z;
                const float rw = a.w + b2.w + c2.w + d2.w;
                cstore64(CxS + bl * 128 + tid,
                         (u64)packbf2(rx, ry) | ((u64)packbf2(rz, rw) << 32));
            }
            __syncthreads();   // drains all CX stores
            if (tid == 0) cstore32(FC + bl * 16, (u32)(t + 1));
        }
    } else {
        // ========== GRU block: 16 dims, 16 b; MFMA A-frags direct from exchange ==========
        const int idx = r - 16, d0 = idx * 16, qc0 = idx * 16;
        float* gh_s = (float*)smraw;                // 768
        float* gi_s = (float*)(smraw + 3072);       // 768
        float* x_s  = (float*)(smraw + 6144);       // 48
        float* wx_s = (float*)(smraw + 6400);       // 144
        float* wo_s = (float*)(smraw + 8192);       // 1539

        const int mn = lane & 15, quad = lane >> 4;

        // ---- pinned B-fragments ----
        short8 bfrag[16];
        if (wv < 3) {                 // gh gate wv: W_hh rows (contiguous k)
            const float* wrow = W_hh + (size_t)(wv * 512 + d0 + mn) * 512;
            #pragma unroll
            for (int kb = 0; kb < 16; ++kb) {
                const int k0 = kb * 32 + quad * 8;
                UQ tpk;
                #pragma unroll
                for (int c = 0; c < 4; ++c)
                    tpk.u[c] = packbf2(wrow[k0 + 2 * c], wrow[k0 + 2 * c + 1]);
                bfrag[kb] = tpk.s;
            }
        } else if (wv < 6) {          // gi gate wv-3: W_ih rows
            const float* wrow = W_ih + (size_t)((wv - 3) * 512 + d0 + mn) * 515;
            #pragma unroll
            for (int kb = 0; kb < 16; ++kb) {
                const int k0 = kb * 32 + quad * 8;
                UQ tpk;
                #pragma unroll
                for (int c = 0; c < 4; ++c)
                    tpk.u[c] = packbf2(wrow[k0 + 2 * c], wrow[k0 + 2 * c + 1]);
                bfrag[kb] = tpk.s;
            }
        } else if (wv == 6) {         // q cols qc0..qc0+15: Wa column gather
            #pragma unroll
            for (int kb = 0; kb < 16; ++kb) {
                const int k0 = kb * 32 + quad * 8;
                UQ tpk;
                #pragma unroll
                for (int c = 0; c < 4; ++c)
                    tpk.u[c] = packbf2(Wa_w[(size_t)(k0 + 2 * c) * 512 + qc0 + mn],
                                       Wa_w[(size_t)(k0 + 2 * c + 1) * 512 + qc0 + mn]);
                bfrag[kb] = tpk.s;
            }
        }
        const float qbias = (wv == 6) ? Wa_b[qc0 + mn] : 0.f;

        if (tid < 144) {
            const int dd = tid / 9, rem = tid - dd * 9, g3 = rem / 3, c = rem - g3 * 3;
            wx_s[tid] = W_ih[(size_t)(g3 * 512 + d0 + dd) * 515 + 512 + c];
        }
        for (int i = tid; i < 1536; i += 512) wo_s[i] = Wo_w[i];
        if (tid < 3) wo_s[1536 + tid] = Wo_b[tid];

        const int gb = tid >> 4, gd = tid & 15;     // gates mapping (tid<256)
        float hold = 0.f, bih[3], bhh[3];
        if (tid < 256) {
            hold = e_last[(size_t)(g * 16 + gb) * 512 + d0 + gd];
            #pragma unroll
            for (int g3 = 0; g3 < 3; ++g3) {
                bih[g3] = b_ih[g3 * 512 + d0 + gd];
                bhh[g3] = b_hh[g3 * 512 + d0 + gd];
            }
        }

        for (int t = 0; t < 64; ++t) {
            const int slot = t & 1;
            const u64* HxS = HX + slot * 2048;
            const u64* CxS = CX + slot * 2048;
            u64* QxS = QX + slot * 8192;
            u64* HxW = HX + ((t + 1) & 1) * 2048;

            if (wv < 3) {
                // ---- gh: poll FH >= t, A-frags direct, 16 MFMA ----
                if (lane < 32) { const u32* f = FH + lane * 16; while (cload32(f) < (u32)t) __builtin_amdgcn_s_sleep(1); }
                u64 adat[32];
                #pragma unroll
                for (int kb = 0; kb < 16; ++kb) {
                    adat[2 * kb]     = cload64(HxS + mn * 128 + kb * 8 + quad * 2);
                    adat[2 * kb + 1] = cload64(HxS + mn * 128 + kb * 8 + quad * 2 + 1);
                }
                f32x4 c = {0.f, 0.f, 0.f, 0.f};
                #pragma unroll
                for (int kb = 0; kb < 16; ++kb) {
                    U16 a; a.d[0] = adat[2 * kb]; a.d[1] = adat[2 * kb + 1];
                    c = __builtin_amdgcn_mfma_f32_16x16x32_bf16(a.s, bfrag[kb], c, 0, 0, 0);
                }
                #pragma unroll
                for (int reg = 0; reg < 4; ++reg)
                    gh_s[((quad * 4 + reg) * 16 + mn) * 3 + wv] = c[reg];
            } else if (wv < 6) {
                // ---- gi: poll FC >= t+1, ctx A-frags direct ----
                if (lane < 16) { const u32* f = FC + lane * 16; while (cload32(f) < (u32)(t + 1)) __builtin_amdgcn_s_sleep(1); }
                u64 adat[32];
                #pragma unroll
                for (int kb = 0; kb < 16; ++kb) {
                    adat[2 * kb]     = cload64(CxS + mn * 128 + kb * 8 + quad * 2);
                    adat[2 * kb + 1] = cload64(CxS + mn * 128 + kb * 8 + quad * 2 + 1);
                }
                f32x4 c = {0.f, 0.f, 0.f, 0.f};
                #pragma unroll
                for (int kb = 0; kb < 16; ++kb) {
                    U16 a; a.d[0] = adat[2 * kb]; a.d[1] = adat[2 * kb + 1];
                    c = __builtin_amdgcn_mfma_f32_16x16x32_bf16(a.s, bfrag[kb], c, 0, 0, 0);
                }
                #pragma unroll
                for (int reg = 0; reg < 4; ++reg)
                    gi_s[((quad * 4 + reg) * 16 + mn) * 3 + (wv - 3)] = c[reg];
            } else if (wv == 6) {
                // ---- q-slice: poll FH >= t, MFMA, tagged store ----
                if (lane < 32) { const u32* f = FH + lane * 16; while (cload32(f) < (u32)t) __builtin_amdgcn_s_sleep(1); }
                u64 adat[32];
                #pragma unroll
                for (int kb = 0; kb < 16; ++kb) {
                    adat[2 * kb]     = cload64(HxS + mn * 128 + kb * 8 + quad * 2);
                    adat[2 * kb + 1] = cload64(HxS + mn * 128 + kb * 8 + quad * 2 + 1);
                }
                f32x4 c = {0.f, 0.f, 0.f, 0.f};
                #pragma unroll
                for (int kb = 0; kb < 16; ++kb) {
                    U16 a; a.d[0] = adat[2 * kb]; a.d[1] = adat[2 * kb + 1];
                    c = __builtin_amdgcn_mfma_f32_16x16x32_bf16(a.s, bfrag[kb], c, 0, 0, 0);
                }
                #pragma unroll
                for (int reg = 0; reg < 4; ++reg) {
                    const int bq = quad * 4 + reg;
                    cstore64(QxS + (size_t)bq * 512 + qc0 + mn,
                             ((u64)(u32)(t + 1) << 32) | (u64)__float_as_uint(c[reg] + qbias));
                }
            } else {
                // ---- wv 7: coords x_{t-1} = h_t @ Wo ----
                if (t > 0) {
                    if (lane < 32) { const u32* f = FH + lane * 16; while (cload32(f) < (u32)t) __builtin_amdgcn_s_sleep(1); }
                    const int cb = lane >> 2, kl = lane & 3;
                    float a0 = 0.f, a1 = 0.f, a2 = 0.f;
                    #pragma unroll 4
                    for (int j = 0; j < 32; ++j) {
                        const u64 v = cload64(HxS + cb * 128 + kl * 32 + j);
                        const float2 p0 = unpackbf2((u32)v), p1 = unpackbf2((u32)(v >> 32));
                        const int d = (kl * 32 + j) * 4;
                        const float* w = wo_s + d * 3;
                        a0 = fmaf(p0.x, w[0], fmaf(p0.y, w[3], fmaf(p1.x, w[6], fmaf(p1.y, w[9],  a0))));
                        a1 = fmaf(p0.x, w[1], fmaf(p0.y, w[4], fmaf(p1.x, w[7], fmaf(p1.y, w[10], a1))));
                        a2 = fmaf(p0.x, w[2], fmaf(p0.y, w[5], fmaf(p1.x, w[8], fmaf(p1.y, w[11], a2))));
                    }
                    a0 += __shfl_xor(a0, 1); a1 += __shfl_xor(a1, 1); a2 += __shfl_xor(a2, 1);
                    a0 += __shfl_xor(a0, 2); a1 += __shfl_xor(a1, 2); a2 += __shfl_xor(a2, 2);
                    if (kl == 0) {
                        x_s[cb * 3 + 0] = a0 + wo_s[1536];
                        x_s[cb * 3 + 1] = a1 + wo_s[1537];
                        x_s[cb * 3 + 2] = a2 + wo_s[1538];
                    }
                } else if (lane < 48) x_s[lane] = 0.f;
            }
            __syncthreads();   // gh_s, gi_s, x_s ready

            if (idx == 0 && t > 0 && tid < 48)
                out[((size_t)(g * 16 + tid / 3) * 64 + (t - 1)) * 3 + tid % 3] = x_s[tid];

            // ---- gates + h update ----
            if (tid < 256) {
                const int ob = (gb * 16 + gd) * 3;
                const float x0 = x_s[gb * 3 + 0], x1 = x_s[gb * 3 + 1], x2 = x_s[gb * 3 + 2];
                const float giR = gi_s[ob + 0] + bih[0]
                                + x0 * wx_s[gd * 9 + 0] + x1 * wx_s[gd * 9 + 1] + x2 * wx_s[gd * 9 + 2];
                const float giZ = gi_s[ob + 1] + bih[1]
                                + x0 * wx_s[gd * 9 + 3] + x1 * wx_s[gd * 9 + 4] + x2 * wx_s[gd * 9 + 5];
                const float giN = gi_s[ob + 2] + bih[2]
                                + x0 * wx_s[gd * 9 + 6] + x1 * wx_s[gd * 9 + 7] + x2 * wx_s[gd * 9 + 8];
                const float ghR = gh_s[ob + 0] + bhh[0];
                const float ghZ = gh_s[ob + 1] + bhh[1];
                const float ghN = gh_s[ob + 2] + bhh[2];
                const float rg = sigm_f(giR + ghR);
                const float zg = sigm_f(giZ + ghZ);
                const float ng = tanh5(giN + rg * ghN);
                const float hnew = (1.f - zg) * ng + zg * hold;
                hold = hnew;
                const float s1 = __shfl_down(hnew, 1);
                const float s2 = __shfl_down(hnew, 2);
                const float s3 = __shfl_down(hnew, 3);
                if ((gd & 3) == 0)
                    cstore64(HxW + gb * 128 + ((d0 + gd) >> 2),
                             (u64)packbf2(hnew, s1) | ((u64)packbf2(s2, s3) << 32));
                if (t == 63)
                    out[OFF_OUT_HT + (size_t)(g * 16 + gb) * 512 + d0 + gd] = hnew;
            }
            __syncthreads();   // drains h stores
            if (tid == 0) cstore32(FH + idx * 16, (u32)(t + 1));
        }

        // ---- final: coords(h_64) -> out[:,63] ----
        if (tid < 32) { const u32* f = FH + tid * 16; while (cload32(f) < 64u) __builtin_amdgcn_s_sleep(1); }
        __syncthreads();
        if (wv == 7) {
            const int cb = lane >> 2, kl = lane & 3;
            float a0 = 0.f, a1 = 0.f, a2 = 0.f;
            #pragma unroll 4
            for (int j = 0; j < 32; ++j) {
                const u64 v = cload64(HX + cb * 128 + kl * 32 + j);   // slot 0 = h_64
                const float2 p0 = unpackbf2((u32)v), p1 = unpackbf2((u32)(v >> 32));
                const int d = (kl * 32 + j) * 4;
                const float* w = wo_s + d * 3;
                a0 = fmaf(p0.x, w[0], fmaf(p0.y, w[3], fmaf(p1.x, w[6], fmaf(p1.y, w[9],  a0))));
                a1 = fmaf(p0.x, w[1], fmaf(p0.y, w[4], fmaf(p1.x, w[7], fmaf(p1.y, w[10], a1))));
                a2 = fmaf(p0.x, w[2], fmaf(p0.y, w[5], fmaf(p1.x, w[8], fmaf(p1.y, w[11], a2))));
            }
            a0 += __shfl_xor(a0, 1); a1 += __shfl_xor(a1, 1); a2 += __shfl_xor(a2, 1);
            a0 += __shfl_xor(a0, 2); a1 += __shfl_xor(a1, 2); a2 += __shfl_xor(a2, 2);
            if (kl == 0) {
                x_s[cb * 3 + 0] = a0 + wo_s[1536];
                x_s[cb * 3 + 1] = a1 + wo_s[1537];
                x_s[cb * 3 + 2] = a2 + wo_s[1538];
            }
        }
        __syncthreads();
        if (idx == 0 && tid < 48)
            out[((size_t)(g * 16 + tid / 3) * 64 + 63) * 3 + tid % 3] = x_s[tid];
    }
}

extern "C" void kernel_launch(void* const* d_in, const int* in_sizes, int n_in,
                              void* d_out, int out_size, void* d_ws, size_t ws_size,
                              hipStream_t stream) {
    const float* e_all  = (const float*)d_in[0];
    const float* e_last = (const float*)d_in[1];
    const float* Wa_w   = (const float*)d_in[2];
    const float* Wa_b   = (const float*)d_in[3];
    const float* Ua_w   = (const float*)d_in[4];
    const float* Ua_b   = (const float*)d_in[5];
    const float* Va_w   = (const float*)d_in[6];
    const float* W_ih   = (const float*)d_in[8];
    const float* W_hh   = (const float*)d_in[9];
    const float* b_ih   = (const float*)d_in[10];
    const float* b_hh   = (const float*)d_in[11];
    const float* Wo_w   = (const float*)d_in[12];
    const float* Wo_b   = (const float*)d_in[13];
    float* outp = (float*)d_out;
    float* ws   = (float*)d_ws;

    hipLaunchKernelGGL(prep_kernel, dim3(512), dim3(256), 0, stream,
                       e_all, e_last, Ua_w, Ua_b, ws);

    void* args[] = { (void*)&e_last, (void*)&Wa_w, (void*)&Wa_b, (void*)&Va_w,
                     (void*)&W_ih, (void*)&W_hh, (void*)&b_ih, (void*)&b_hh,
                     (void*)&Wo_w, (void*)&Wo_b, (void*)&outp, (void*)&ws };
    hipError_t err = hipLaunchCooperativeKernel((void*)decode_kernel, dim3(NBLK), dim3(NTHR),
                                                args, 0, stream);
    if (err != hipSuccess) {
        // fallback: 192 blocks <= 256 CUs, trivially co-resident
        hipLaunchKernelGGL(decode_kernel, dim3(NBLK), dim3(NTHR), 0, stream,
                           e_last, Wa_w, Wa_b, Va_w, W_ih, W_hh, b_ih, b_hh,
                           Wo_w, Wo_b, outp, ws);
    }
}